// Round 11
// baseline (288.447 us; speedup 1.0000x reference)
//
#include <hip/hip_runtime.h>

// MoE fused forward: out = (relu(x@W1[e]+b1[e])@W2[e]+b2[e]) * exp(min(T, log100))
// N=524288, D=128, H=512, E=8, contiguous expert chunks.
// R11: producer branch identical to R10 (178us). Consumer re-tiled to halve the
// dominant LDS term (ha reads were 512KB/tile = 55% of the saturated LDS pipe):
// wave (th,dq) owns 32tok x 32d -> ha reads 4KB/chunk/wave (was 8KB).
// w2 B-fragments no longer fit regs at 32d (128 VGPR) -> streamed from L2 per
// chunk (w2t is 1MB, L2-resident; 4 x s16x8/wave/interval, dbuf slot c&1,
// issued one interval ahead of use). acc2 stays 16 f32; no reduction needed.
// LDS bytes/tile: 940 -> ~684 KB (-27%). Consumer regs ~87.

#define CLAMP_MAXV 4.605170185988091f

typedef __attribute__((ext_vector_type(8))) short s16x8;
typedef __attribute__((ext_vector_type(4))) float f32x4;
typedef __attribute__((ext_vector_type(4))) unsigned short u16x4;
typedef __attribute__((ext_vector_type(8))) unsigned short u16x8;

static __device__ __forceinline__ unsigned short f2bf(float f) {
  union { float f; unsigned int u; } v; v.f = f;
  unsigned int r = v.u + 0x7FFFu + ((v.u >> 16) & 1u);  // RNE
  return (unsigned short)(r >> 16);
}

static __device__ __forceinline__ void gll16(const void* src, void* dst) {
  __builtin_amdgcn_global_load_lds((const __attribute__((address_space(1))) void*)src,
                                   (__attribute__((address_space(3))) void*)dst, 16, 0, 0);
}

// LDS-only barrier: own-wave lgkm drain + s_barrier (vmcnt NOT drained; in-flight
// VMEM are reg loads, waited by compiler before use).
#define LBAR() do { \
  asm volatile("s_waitcnt lgkmcnt(0)" ::: "memory"); \
  __builtin_amdgcn_s_barrier(); \
  __builtin_amdgcn_sched_barrier(0); \
} while (0)

// ---- pre-kernel: W1[e][d][h] -> w1t[e][h][d] bf16 ; W2[e][h][d] -> w2t[e][d][h] bf16
__global__ void conv_w(const float* __restrict__ W1, const float* __restrict__ W2,
                       unsigned short* __restrict__ w1t, unsigned short* __restrict__ w2t) {
  int idx = blockIdx.x * 256 + threadIdx.x;  // 131072 total
  if (idx < 65536) {
    int h  = idx & 511;
    int d0 = ((idx >> 9) & 15) << 3;
    int e  = idx >> 13;
    const float* src = W1 + ((size_t)e << 16);
    u16x8 v;
#pragma unroll
    for (int j = 0; j < 8; ++j) v[j] = f2bf(src[(size_t)(d0 + j) * 512 + h]);
    *(u16x8*)(w1t + ((((size_t)e << 9) + h) << 7) + d0) = v;
  } else {
    int i2 = idx - 65536;
    int d  = i2 & 127;
    int h0 = ((i2 >> 7) & 63) << 3;
    int e  = i2 >> 13;
    const float* src = W2 + ((size_t)e << 16);
    u16x8 v;
#pragma unroll
    for (int j = 0; j < 8; ++j) v[j] = f2bf(src[(size_t)(h0 + j) * 128 + d]);
    *(u16x8*)(w2t + ((((size_t)e << 7) + d) << 9) + h0) = v;
  }
}

// ---- fused MoE kernel (wave-specialized)
__global__ __launch_bounds__(1024, 4) void moe_fused(
    const float* __restrict__ x,
    const float* __restrict__ b1,
    const float* __restrict__ b2,
    const float* __restrict__ temp,
    const unsigned short* __restrict__ w1t,
    const unsigned short* __restrict__ w2t,
    float* __restrict__ out)
{
  __shared__ __align__(16) char smem[133120];
  char* const w1s  = smem;             // 96 KB [h=128..511][128 d] bf16, swz ^((h&7)<<4)
  char* const hsb0 = smem + 98304;     //  8 KB [64 tok][64 h] bf16, swz ^((tok&7)<<4)
  char* const hsb1 = smem + 106496;    //  8 KB
  char* const xs   = smem + 114688;    // 16 KB [64 tok][128 d] bf16 (NOT aliased)
  float* const b1s = (float*)(smem + 131072);  // 2 KB

  const int tid  = threadIdx.x;
  const int lane = tid & 63;
  const int wid  = tid >> 6;          // 0..15
  const int l15  = lane & 15;
  const int lg   = lane >> 4;
  const int blk  = blockIdx.x;
  const int e    = blk >> 6;          // 64 blocks per expert
  const size_t tok0 = (size_t)blk << 10;   // 1024 tokens per block

  const unsigned short* w1g = w1t + ((size_t)e << 16);
  const unsigned short* w2g = w2t + ((size_t)e << 16);
  const float* xblk = x + (tok0 << 7);
  float* const oblk = out + (tok0 << 7);

  // ---- prologue: stage w1 rows 128..511 (96 KB) once, source pre-swizzled
#pragma unroll
  for (int k = 0; k < 6; ++k) {
    int s = tid + (k << 10);          // 0..6143 slots of 16 B
    int hl = s >> 4, sr = s & 15;     // LDS row 0..383 == global h-128
    gll16(w1g + ((size_t)(hl + 128) << 7) + ((sr ^ (hl & 7)) << 3), w1s + (s << 4));
  }

  if (tid < 512) b1s[tid] = b1[(e << 9) + tid];

  // x tile 0 into regs (each thread owns 8 floats)
  f32x4 xv[2];
  xv[0] = *(const f32x4*)(xblk + (tid << 3));
  xv[1] = *(const f32x4*)(xblk + (tid << 3) + 4);

  // xs-write address: tok = tid>>4, col = (tid&15)*8
  const int xtok = tid >> 4;
  const unsigned xaddr = (unsigned)((xtok << 8) + ((tid & 15) << 4)) ^ (unsigned)((xtok & 7) << 4);

  if (wid < 8) {
    // ================= PRODUCER: GEMM1 (identical to R10) =================
    const int hr  = wid & 3;
    const int tq0 = (wid >> 2) << 5;
    const unsigned hl2 = (unsigned)(((hr << 4) + (lg << 2)) << 1);

    // w1 chunks 0-1 fragments in regs (loaded from global/L2, plain [h][d] layout)
    s16x8 w1r[2][4];
#pragma unroll
    for (int c = 0; c < 2; ++c) {
      const int hrow = (c << 6) + (hr << 4) + l15;
#pragma unroll
      for (int ks = 0; ks < 4; ++ks)
        w1r[c][ks] = *(const s16x8*)(w1g + ((size_t)hrow << 7) + (ks << 5) + (lg << 3));
    }

    __syncthreads();  // full drain: w1s + b1s landed

#pragma unroll 1
    for (int t = 0; t < 16; ++t) {
      // write xs
      u16x8 p;
#pragma unroll
      for (int i = 0; i < 8; ++i) p[i] = f2bf(xv[i >> 2][i & 3]);
      *(u16x8*)(xs + xaddr) = p;
      LBAR();   // xs visible

      // hoist x fragments; no barrier needed after (xs not rewritten for 10 barriers)
      s16x8 xb[2][4];
#pragma unroll
      for (int j = 0; j < 2; ++j) {
        int tk = tq0 + (j << 4) + l15;
#pragma unroll
        for (int ks = 0; ks < 4; ++ks) {
          unsigned koff = (unsigned)((ks << 6) + (lg << 4));
          xb[j][ks] = *(const s16x8*)(xs + (((unsigned)(tk << 8) + koff) ^ (unsigned)((tk & 7) << 4)));
        }
      }

#pragma unroll
      for (int c = 0; c <= 8; ++c) {
        if (c < 8) {
          f32x4 bias = *(const f32x4*)(b1s + (c << 6) + (hr << 4) + (lg << 2));
          f32x4 acc1[2];
          acc1[0] = (f32x4){0.f, 0.f, 0.f, 0.f};
          acc1[1] = (f32x4){0.f, 0.f, 0.f, 0.f};
          if (c < 2) {
#pragma unroll
            for (int j = 0; j < 2; ++j)
#pragma unroll
              for (int ks = 0; ks < 4; ++ks)
                acc1[j] = __builtin_amdgcn_mfma_f32_16x16x32_bf16(w1r[c][ks], xb[j][ks], acc1[j], 0, 0, 0);
          } else {
            const int hrow = (c << 6) + (hr << 4) + l15;   // global h (>=128)
            const unsigned hswz = (unsigned)((hrow & 7) << 4);
            s16x8 a[4];
#pragma unroll
            for (int ks = 0; ks < 4; ++ks) {
              unsigned koff = (unsigned)((ks << 6) + (lg << 4));
              a[ks] = *(const s16x8*)(w1s + (((unsigned)((hrow - 128) << 8) + koff) ^ hswz));
            }
#pragma unroll
            for (int j = 0; j < 2; ++j)
#pragma unroll
              for (int ks = 0; ks < 4; ++ks)
                acc1[j] = __builtin_amdgcn_mfma_f32_16x16x32_bf16(a[ks], xb[j][ks], acc1[j], 0, 0, 0);
          }

          char* const hw = (c & 1) ? hsb1 : hsb0;
#pragma unroll
          for (int j = 0; j < 2; ++j) {
            int tk = tq0 + (j << 4) + l15;
            u16x4 qv;
#pragma unroll
            for (int r = 0; r < 4; ++r)
              qv[r] = f2bf(fmaxf(acc1[j][r] + bias[r], 0.f));
            *(u16x4*)(hw + (((unsigned)(tk << 7) + hl2) ^ (unsigned)((tk & 7) << 4))) = qv;
          }
        }
        if (c == 4 && t < 15) {
          const float* xn = xblk + (((size_t)t + 1) << 13);
          xv[0] = *(const f32x4*)(xn + (tid << 3));
          xv[1] = *(const f32x4*)(xn + (tid << 3) + 4);
        }
        LBAR();
      }
    }
  } else {
    // ================= CONSUMER: GEMM2 + store (32tok x 32d waves) =========
    const int cw = wid - 8;
    const int th = cw >> 2;           // 0..1 token half
    const int dq = cw & 3;            // 0..3 d-quarter
    const int d0 = (dq << 5) + l15;   // j=0 column; j=1 column = d0+16

    const float b2v0  = b2[(e << 7) + d0];
    const float b2v1  = b2[(e << 7) + d0 + 16];
    const float scale = expf(fminf(temp[0], CLAMP_MAXV));

    // w2 fragment lane base (chunk offset added in-loop); w2t is [d][h] k-contig
    const unsigned short* w2base0 = w2g + ((size_t)d0 << 9) + (lg << 3);
    const unsigned short* w2base1 = w2g + ((size_t)(d0 + 16) << 9) + (lg << 3);

    __syncthreads();  // full drain: matches producer barrier

    // w2 fragment double buffer, statically indexed after unroll: [slot][ks]
    s16x8 w2s0[2][2], w2s1[2][2];

#pragma unroll 1
    for (int t = 0; t < 16; ++t) {
      // write xs (same mapping as producers)
      u16x8 p;
#pragma unroll
      for (int i = 0; i < 8; ++i) p[i] = f2bf(xv[i >> 2][i & 3]);
      *(u16x8*)(xs + xaddr) = p;
      LBAR();

      f32x4 acc2[2][2];
#pragma unroll
      for (int ii = 0; ii < 2; ++ii)
#pragma unroll
        for (int j = 0; j < 2; ++j) acc2[ii][j] = (f32x4){0.f, 0.f, 0.f, 0.f};

#pragma unroll
      for (int c = 0; c <= 8; ++c) {
        if (c < 8) {
          // issue chunk-c w2 fragment loads into slot c&1 (consumed at interval c+1;
          // slot c&1 was last read at interval c-1 -> free). L2-resident (1MB).
          const int sl = c & 1;
#pragma unroll
          for (int ks = 0; ks < 2; ++ks) {
            if (sl == 0) {
              w2s0[0][ks] = *(const s16x8*)(w2base0 + (c << 6) + (ks << 5));
              w2s1[0][ks] = *(const s16x8*)(w2base1 + (c << 6) + (ks << 5));
            } else {
              w2s0[1][ks] = *(const s16x8*)(w2base0 + (c << 6) + (ks << 5));
              w2s1[1][ks] = *(const s16x8*)(w2base1 + (c << 6) + (ks << 5));
            }
          }
        }
        if (c >= 1) {
          const int cc = c - 1;
          char* const hrd = (cc & 1) ? hsb1 : hsb0;
#pragma unroll
          for (int ii = 0; ii < 2; ++ii) {
            int tk = (th << 5) + (ii << 4) + l15;
            unsigned tswz = (unsigned)((tk & 7) << 4);
#pragma unroll
            for (int ks = 0; ks < 2; ++ks) {
              unsigned koff = (unsigned)((ks << 6) + (lg << 4));
              s16x8 ha = *(const s16x8*)(hrd + (((unsigned)(tk << 7) + koff) ^ tswz));
              if ((cc & 1) == 0) {
                acc2[ii][0] = __builtin_amdgcn_mfma_f32_16x16x32_bf16(ha, w2s0[0][ks], acc2[ii][0], 0, 0, 0);
                acc2[ii][1] = __builtin_amdgcn_mfma_f32_16x16x32_bf16(ha, w2s1[0][ks], acc2[ii][1], 0, 0, 0);
              } else {
                acc2[ii][0] = __builtin_amdgcn_mfma_f32_16x16x32_bf16(ha, w2s0[1][ks], acc2[ii][0], 0, 0, 0);
                acc2[ii][1] = __builtin_amdgcn_mfma_f32_16x16x32_bf16(ha, w2s1[1][ks], acc2[ii][1], 0, 0, 0);
              }
            }
          }
        }
        if (c == 4 && t < 15) {
          const float* xn = xblk + (((size_t)t + 1) << 13);
          xv[0] = *(const f32x4*)(xn + (tid << 3));
          xv[1] = *(const f32x4*)(xn + (tid << 3) + 4);
        }
        LBAR();
      }

      // store tile t: wave covers 32 tok x 32 d
      float* og = oblk + ((size_t)t << 13);
#pragma unroll
      for (int ii = 0; ii < 2; ++ii) {
#pragma unroll
        for (int r = 0; r < 4; ++r) {
          int tk = (th << 5) + (ii << 4) + (lg << 2) + r;
          og[((size_t)tk << 7) + d0]      = (acc2[ii][0][r] + b2v0) * scale;
          og[((size_t)tk << 7) + d0 + 16] = (acc2[ii][1][r] + b2v1) * scale;
        }
      }
    }
  }
}

// ---- fallback (only if ws_size is tiny): naive but correct
__global__ void moe_naive(const float* __restrict__ x, const float* __restrict__ W1,
                          const float* __restrict__ b1, const float* __restrict__ W2,
                          const float* __restrict__ b2, const float* __restrict__ temp,
                          float* __restrict__ out) {
  __shared__ float xr[128];
  __shared__ float hrow[512];
  int t = blockIdx.x;
  int e = t >> 16;
  int tx = threadIdx.x;
  xr[tx] = x[((size_t)t << 7) + tx];
  __syncthreads();
  const float* w1e = W1 + ((size_t)e << 16);
  for (int h = tx; h < 512; h += 128) {
    float s = b1[(e << 9) + h];
    for (int d = 0; d < 128; ++d) s += xr[d] * w1e[(size_t)d * 512 + h];
    hrow[h] = fmaxf(s, 0.f);
  }
  __syncthreads();
  const float* w2e = W2 + ((size_t)e << 16);
  float s = b2[(e << 7) + tx];
  for (int h = 0; h < 512; ++h) s += hrow[h] * w2e[(size_t)h * 128 + tx];
  out[((size_t)t << 7) + tx] = s * expf(fminf(temp[0], CLAMP_MAXV));
}

extern "C" void kernel_launch(void* const* d_in, const int* in_sizes, int n_in,
                              void* d_out, int out_size, void* d_ws, size_t ws_size,
                              hipStream_t stream) {
  const float* x    = (const float*)d_in[0];
  const float* W1   = (const float*)d_in[1];
  const float* b1   = (const float*)d_in[2];
  const float* W2   = (const float*)d_in[3];
  const float* b2   = (const float*)d_in[4];
  const float* temp = (const float*)d_in[5];
  float* out = (float*)d_out;

  const size_t WS_NEEDED = 2u * 524288u * sizeof(unsigned short);  // 2 MB
  if (ws_size >= WS_NEEDED) {
    unsigned short* w1t = (unsigned short*)d_ws;
    unsigned short* w2t = w1t + 524288;
    conv_w<<<512, 256, 0, stream>>>(W1, W2, w1t, w2t);
    moe_fused<<<512, 1024, 0, stream>>>(x, b1, b2, temp, w1t, w2t, out);
  } else {
    moe_naive<<<524288, 128, 0, stream>>>(x, W1, b1, W2, b2, temp, out);
  }
}

// Round 12
// 214.725 us; speedup vs baseline: 1.3433x; 1.3433x over previous
//
#include <hip/hip_runtime.h>

// MoE fused forward: out = (relu(x@W1[e]+b1[e])@W2[e]+b2[e]) * exp(min(T, log100))
// N=524288, D=128, H=512, E=8, contiguous expert chunks.
// R12: 2 BLOCKS/CU. R6/R10 roles + consumer (w2f 64 VGPR) unchanged, but w1 is
// ring-staged per chunk (2 x 16KB dbuf, gll16 1-ahead: all 1024 threads stage
// 16B each; w1t re-read from L2 每 tile ~= 1GB/dispatch ~= 7 TB/s, coalesced).
// LDS 66KB -> 2 blocks/CU (512-block grid fully co-resident); all interval
// barriers are __syncthreads (vmcnt drained -> no staging races; drain stalls
// hidden by the other resident block, m114). R11's lesson applied: no
// per-interval strided global reads anywhere.

#define CLAMP_MAXV 4.605170185988091f

typedef __attribute__((ext_vector_type(8))) short s16x8;
typedef __attribute__((ext_vector_type(4))) float f32x4;
typedef __attribute__((ext_vector_type(4))) unsigned short u16x4;
typedef __attribute__((ext_vector_type(8))) unsigned short u16x8;

static __device__ __forceinline__ unsigned short f2bf(float f) {
  union { float f; unsigned int u; } v; v.f = f;
  unsigned int r = v.u + 0x7FFFu + ((v.u >> 16) & 1u);  // RNE
  return (unsigned short)(r >> 16);
}

static __device__ __forceinline__ void gll16(const void* src, void* dst) {
  __builtin_amdgcn_global_load_lds((const __attribute__((address_space(1))) void*)src,
                                   (__attribute__((address_space(3))) void*)dst, 16, 0, 0);
}

// ---- pre-kernel: W1[e][d][h] -> w1t[e][h][d] bf16 ; W2[e][h][d] -> w2t[e][d][h] bf16
__global__ void conv_w(const float* __restrict__ W1, const float* __restrict__ W2,
                       unsigned short* __restrict__ w1t, unsigned short* __restrict__ w2t) {
  int idx = blockIdx.x * 256 + threadIdx.x;  // 131072 total
  if (idx < 65536) {
    int h  = idx & 511;
    int d0 = ((idx >> 9) & 15) << 3;
    int e  = idx >> 13;
    const float* src = W1 + ((size_t)e << 16);
    u16x8 v;
#pragma unroll
    for (int j = 0; j < 8; ++j) v[j] = f2bf(src[(size_t)(d0 + j) * 512 + h]);
    *(u16x8*)(w1t + ((((size_t)e << 9) + h) << 7) + d0) = v;
  } else {
    int i2 = idx - 65536;
    int d  = i2 & 127;
    int h0 = ((i2 >> 7) & 63) << 3;
    int e  = i2 >> 13;
    const float* src = W2 + ((size_t)e << 16);
    u16x8 v;
#pragma unroll
    for (int j = 0; j < 8; ++j) v[j] = f2bf(src[(size_t)(h0 + j) * 128 + d]);
    *(u16x8*)(w2t + ((((size_t)e << 7) + d) << 9) + h0) = v;
  }
}

// Stage w1 chunk cn (64 h rows, 16 KB) into dst; one gll16 (16 B) per thread.
// Source pre-swizzled so LDS is linear-dest + read-side XOR (rule #21).
static __device__ __forceinline__ void stage_w1_chunk(
    const unsigned short* __restrict__ w1g, char* dst, int cn, int tid) {
  int hl = tid >> 4, sr = tid & 15;   // local h row 0..63, 16B slot 0..15
  gll16(w1g + ((size_t)((cn << 6) + hl) << 7) + ((sr ^ (hl & 7)) << 3),
        dst + (tid << 4));
}

// ---- fused MoE kernel (wave-specialized, 2 blocks/CU)
__global__ __launch_bounds__(1024, 4) void moe_fused(
    const float* __restrict__ x,
    const float* __restrict__ b1,
    const float* __restrict__ b2,
    const float* __restrict__ temp,
    const unsigned short* __restrict__ w1t,
    const unsigned short* __restrict__ w2t,
    float* __restrict__ out)
{
  __shared__ __align__(16) char smem[67584];
  char* const w1b0 = smem;            // 16 KB [64 h][128 d] bf16, swz ^((hl&7)<<4)
  char* const w1b1 = smem + 16384;    // 16 KB
  char* const hsb0 = smem + 32768;    //  8 KB [64 tok][64 h] bf16, swz ^((tok&7)<<4)
  char* const hsb1 = smem + 40960;    //  8 KB
  char* const xs   = smem + 49152;    // 16 KB [64 tok][128 d] bf16
  float* const b1s = (float*)(smem + 65536);  // 2 KB

  const int tid  = threadIdx.x;
  const int lane = tid & 63;
  const int wid  = tid >> 6;          // 0..15
  const int l15  = lane & 15;
  const int lg   = lane >> 4;
  const int blk  = blockIdx.x;
  const int e    = blk >> 6;          // 64 blocks per expert
  const size_t tok0 = (size_t)blk << 10;   // 1024 tokens per block

  const unsigned short* w1g = w1t + ((size_t)e << 16);
  const unsigned short* w2g = w2t + ((size_t)e << 16);
  const float* xblk = x + (tok0 << 7);
  float* const oblk = out + (tok0 << 7);

  // ---- prologue: stage w1 chunk 0; b1s; x tile 0 to regs
  stage_w1_chunk(w1g, w1b0, 0, tid);
  if (tid < 512) b1s[tid] = b1[(e << 9) + tid];

  f32x4 xv[2];
  xv[0] = *(const f32x4*)(xblk + (tid << 3));
  xv[1] = *(const f32x4*)(xblk + (tid << 3) + 4);

  // xs-write address: tok = tid>>4, col = (tid&15)*8
  const int xtok = tid >> 4;
  const unsigned xaddr = (unsigned)((xtok << 8) + ((tid & 15) << 4)) ^ (unsigned)((xtok & 7) << 4);

  if (wid < 8) {
    // ================= PRODUCER: GEMM1 =================
    const int hr  = wid & 3;
    const int tq0 = (wid >> 2) << 5;
    const unsigned hl2 = (unsigned)(((hr << 4) + (lg << 2)) << 1);
    const int hrl = (hr << 4) + l15;                 // local h row 0..63
    const unsigned hswz = (unsigned)((hrl & 7) << 4);

    __syncthreads();  // chunk 0 + b1s landed

#pragma unroll 1
    for (int t = 0; t < 16; ++t) {
      // write xs
      u16x8 p;
#pragma unroll
      for (int i = 0; i < 8; ++i) p[i] = f2bf(xv[i >> 2][i & 3]);
      *(u16x8*)(xs + xaddr) = p;
      __syncthreads();   // xs visible

      // hoist x fragments (xs not rewritten until next tile)
      s16x8 xb[2][4];
#pragma unroll
      for (int j = 0; j < 2; ++j) {
        int tk = tq0 + (j << 4) + l15;
#pragma unroll
        for (int ks = 0; ks < 4; ++ks) {
          unsigned koff = (unsigned)((ks << 6) + (lg << 4));
          xb[j][ks] = *(const s16x8*)(xs + (((unsigned)(tk << 8) + koff) ^ (unsigned)((tk & 7) << 4)));
        }
      }

#pragma unroll
      for (int c = 0; c <= 8; ++c) {
        if (c < 8) {
          // stage next chunk ((c+1)&7) into the other buffer
          stage_w1_chunk(w1g, ((c + 1) & 1) ? w1b1 : w1b0, (c + 1) & 7, tid);

          char* const wcur = (c & 1) ? w1b1 : w1b0;
          s16x8 a[4];
#pragma unroll
          for (int ks = 0; ks < 4; ++ks) {
            unsigned koff = (unsigned)((ks << 6) + (lg << 4));
            a[ks] = *(const s16x8*)(wcur + (((unsigned)(hrl << 8) + koff) ^ hswz));
          }
          f32x4 bias = *(const f32x4*)(b1s + (c << 6) + (hr << 4) + (lg << 2));
          f32x4 acc1[2];
          acc1[0] = (f32x4){0.f, 0.f, 0.f, 0.f};
          acc1[1] = (f32x4){0.f, 0.f, 0.f, 0.f};
#pragma unroll
          for (int j = 0; j < 2; ++j)
#pragma unroll
            for (int ks = 0; ks < 4; ++ks)
              acc1[j] = __builtin_amdgcn_mfma_f32_16x16x32_bf16(a[ks], xb[j][ks], acc1[j], 0, 0, 0);

          char* const hw = (c & 1) ? hsb1 : hsb0;
#pragma unroll
          for (int j = 0; j < 2; ++j) {
            int tk = tq0 + (j << 4) + l15;
            u16x4 qv;
#pragma unroll
            for (int r = 0; r < 4; ++r)
              qv[r] = f2bf(fmaxf(acc1[j][r] + bias[r], 0.f));
            *(u16x4*)(hw + (((unsigned)(tk << 7) + hl2) ^ (unsigned)((tk & 7) << 4))) = qv;
          }
        }
        if (c == 4 && t < 15) {
          const float* xn = xblk + (((size_t)t + 1) << 13);
          xv[0] = *(const f32x4*)(xn + (tid << 3));
          xv[1] = *(const f32x4*)(xn + (tid << 3) + 4);
        }
        __syncthreads();   // chunk c+1 landed; hsb[c&1] visible; all reads drained
      }
    }
  } else {
    // ================= CONSUMER: GEMM2 + store =================
    const int cw = wid - 8;
    const int dlane = (cw << 4) + l15;

    // w2 fragments: wave owns d-slice [cw*16, cw*16+16), all 512 h (64 VGPR)
    s16x8 w2f[8][2];
#pragma unroll
    for (int c = 0; c < 8; ++c)
#pragma unroll
      for (int ks = 0; ks < 2; ++ks)
        w2f[c][ks] = *(const s16x8*)(w2g + ((size_t)dlane << 9) + (c << 6) + (ks << 5) + (lg << 3));

    const float b2v   = b2[(e << 7) + dlane];
    const float scale = expf(fminf(temp[0], CLAMP_MAXV));

    __syncthreads();  // matches producer prologue barrier

#pragma unroll 1
    for (int t = 0; t < 16; ++t) {
      // write xs (same mapping as producers)
      u16x8 p;
#pragma unroll
      for (int i = 0; i < 8; ++i) p[i] = f2bf(xv[i >> 2][i & 3]);
      *(u16x8*)(xs + xaddr) = p;
      __syncthreads();

      f32x4 acc2[4];
#pragma unroll
      for (int i = 0; i < 4; ++i) acc2[i] = (f32x4){0.f, 0.f, 0.f, 0.f};

#pragma unroll
      for (int c = 0; c <= 8; ++c) {
        if (c < 8) {
          // co-stage next w1 chunk (shared staging duty)
          stage_w1_chunk(w1g, ((c + 1) & 1) ? w1b1 : w1b0, (c + 1) & 7, tid);
        }
        if (c >= 1) {
          const int cc = c - 1;
          char* const hrd = (cc & 1) ? hsb1 : hsb0;
#pragma unroll
          for (int ii = 0; ii < 4; ++ii) {
            int tk = (ii << 4) + l15;
            unsigned tswz = (unsigned)((tk & 7) << 4);
#pragma unroll
            for (int ks = 0; ks < 2; ++ks) {
              unsigned koff = (unsigned)((ks << 6) + (lg << 4));
              s16x8 ha = *(const s16x8*)(hrd + (((unsigned)(tk << 7) + koff) ^ tswz));
              acc2[ii] = __builtin_amdgcn_mfma_f32_16x16x32_bf16(ha, w2f[cc][ks], acc2[ii], 0, 0, 0);
            }
          }
        }
        if (c == 4 && t < 15) {
          const float* xn = xblk + (((size_t)t + 1) << 13);
          xv[0] = *(const f32x4*)(xn + (tid << 3));
          xv[1] = *(const f32x4*)(xn + (tid << 3) + 4);
        }
        __syncthreads();
      }

      // store tile t: wave covers all 64 tok x its 16 d
      float* og = oblk + ((size_t)t << 13);
#pragma unroll
      for (int i = 0; i < 4; ++i) {
#pragma unroll
        for (int r = 0; r < 4; ++r) {
          int tk = (i << 4) + (lg << 2) + r;
          og[((size_t)tk << 7) + dlane] = (acc2[i][r] + b2v) * scale;
        }
      }
    }
  }
}

// ---- fallback (only if ws_size is tiny): naive but correct
__global__ void moe_naive(const float* __restrict__ x, const float* __restrict__ W1,
                          const float* __restrict__ b1, const float* __restrict__ W2,
                          const float* __restrict__ b2, const float* __restrict__ temp,
                          float* __restrict__ out) {
  __shared__ float xr[128];
  __shared__ float hrow[512];
  int t = blockIdx.x;
  int e = t >> 16;
  int tx = threadIdx.x;
  xr[tx] = x[((size_t)t << 7) + tx];
  __syncthreads();
  const float* w1e = W1 + ((size_t)e << 16);
  for (int h = tx; h < 512; h += 128) {
    float s = b1[(e << 9) + h];
    for (int d = 0; d < 128; ++d) s += xr[d] * w1e[(size_t)d * 512 + h];
    hrow[h] = fmaxf(s, 0.f);
  }
  __syncthreads();
  const float* w2e = W2 + ((size_t)e << 16);
  float s = b2[(e << 7) + tx];
  for (int h = 0; h < 512; ++h) s += hrow[h] * w2e[(size_t)h * 128 + tx];
  out[((size_t)t << 7) + tx] = s * expf(fminf(temp[0], CLAMP_MAXV));
}

extern "C" void kernel_launch(void* const* d_in, const int* in_sizes, int n_in,
                              void* d_out, int out_size, void* d_ws, size_t ws_size,
                              hipStream_t stream) {
  const float* x    = (const float*)d_in[0];
  const float* W1   = (const float*)d_in[1];
  const float* b1   = (const float*)d_in[2];
  const float* W2   = (const float*)d_in[3];
  const float* b2   = (const float*)d_in[4];
  const float* temp = (const float*)d_in[5];
  float* out = (float*)d_out;

  const size_t WS_NEEDED = 2u * 524288u * sizeof(unsigned short);  // 2 MB
  if (ws_size >= WS_NEEDED) {
    unsigned short* w1t = (unsigned short*)d_ws;
    unsigned short* w2t = w1t + 524288;
    conv_w<<<512, 256, 0, stream>>>(W1, W2, w1t, w2t);
    moe_fused<<<512, 1024, 0, stream>>>(x, b1, b2, temp, w1t, w2t, out);
  } else {
    moe_naive<<<524288, 128, 0, stream>>>(x, W1, b1, W2, b2, temp, out);
  }
}